// Round 10
// baseline (440.040 us; speedup 1.0000x reference)
//
#include <hip/hip_runtime.h>

// GCN 2-layer, 5 dispatches:
//   binA:   chunk-wise LDS counting sort of edges by dst-bucket (512 nodes),
//           64B-aligned reservations into fixed per-bucket regions (CAP slots)
//   degxd:  per-bucket degree hist -> dis, fused xd = bf16(dis*x) (32B rows)
//   layer1B: per-bucket: gather xd[src] (L2-resident 3.2MB) -> LDS f32 atomic
//           accumulate y[512][16]; then per-node MLP (W1,b1,relu,W2) -> g2
//   out2B:  per-bucket: gather g2[src] -> LDS accumulate -> out
// norm trick: g = dis*(h@W); out[v] = dis[v]*(sum_{u->v} g[u] + g[v]) + b,
// and layer1 aggregates BEFORE the GEMM (linearity of @W1).

static constexpr int F0 = 16;
static constexpr int F1 = 32;
static constexpr int F2 = 2;
static constexpr int BSH  = 9;      // bucket = dst>>9 (512 nodes)
static constexpr int BMSK = 511;
static constexpr int NPB  = 512;    // nodes per bucket
static constexpr int MAXNB = 256;   // max buckets (N <= 131072)
static constexpr int BPAD  = 16;    // cursor padded to own 64B line
static constexpr int EPB   = 8192;  // edges per binA chunk
static constexpr int CAP   = 24576; // slots per bucket region (exp ~19.3k)
static constexpr int SORTCAP = EPB + MAXNB * 16;   // 12288
static constexpr unsigned SENT = 0xFFFFFFFFu;

__device__ inline unsigned roundup16(unsigned h) { return (h + 15u) & ~15u; }

__device__ inline unsigned f2bf(float f) {
    unsigned u = __float_as_uint(f);
    return (u + 0x7fffu + ((u >> 16) & 1u)) >> 16;   // RNE
}
__device__ inline float bf2f(unsigned b) {
    return __uint_as_float(b << 16);
}

// LDS counting sort of a chunk, then per-bucket wave burst copy to global.
// Reservation: bs = b*CAP + atomic cursor (bfill starts at 0), roundup16 ->
// every region 64B-aligned & exclusively owned; pads carry SENT.
__global__ __launch_bounds__(512) void k_binA(const int* __restrict__ src,
                                              const int* __restrict__ dst,
                                              unsigned* __restrict__ bfill,
                                              unsigned* __restrict__ pairs,
                                              int E, int nb) {
    __shared__ unsigned h[MAXNB];
    __shared__ unsigned lbase[MAXNB];
    __shared__ unsigned bs[MAXNB];
    __shared__ unsigned cur[MAXNB];
    __shared__ __attribute__((aligned(16))) unsigned sorted[SORTCAP];
    int tid = threadIdx.x;
    for (int b = tid; b < MAXNB; b += 512) { h[b] = 0; cur[b] = 0; }
    for (int i = tid; i < SORTCAP; i += 512) sorted[i] = SENT;
    __syncthreads();
    int e0 = blockIdx.x * EPB;
    int e1 = min(e0 + EPB, E);
    for (int e = e0 + tid; e < e1; e += 512)
        atomicAdd(&h[((unsigned)dst[e]) >> BSH], 1u);
    __syncthreads();
    if (tid < MAXNB) lbase[tid] = roundup16(h[tid]);
    __syncthreads();
    for (int off = 1; off < MAXNB; off <<= 1) {
        unsigned t = (tid >= off && tid < MAXNB) ? lbase[tid - off] : 0u;
        __syncthreads();
        if (tid < MAXNB) lbase[tid] += t;
        __syncthreads();
    }
    if (tid < MAXNB) lbase[tid] -= roundup16(h[tid]);   // exclusive
    if (tid < nb && h[tid])
        bs[tid] = (unsigned)(tid * CAP) + atomicAdd(&bfill[tid * BPAD], roundup16(h[tid]));
    __syncthreads();
    for (int e = e0 + tid; e < e1; e += 512) {
        unsigned d = (unsigned)dst[e];
        unsigned b = d >> BSH;
        unsigned pos = lbase[b] + atomicAdd(&cur[b], 1u);
        sorted[pos] = (((unsigned)src[e]) << BSH) | (d & BMSK);
    }
    __syncthreads();
    int wid = tid >> 6;
    int lane = tid & 63;
    for (int b = wid; b < nb; b += 8) {
        unsigned np = roundup16(h[b]) >> 2;   // uint4 count
        if (!np) continue;
        const uint4* sp = reinterpret_cast<const uint4*>(&sorted[lbase[b]]);
        uint4* gp = reinterpret_cast<uint4*>(&pairs[bs[b]]);
        for (unsigned k = lane; k < np; k += 64) gp[k] = sp[k];
    }
}

// per-bucket: degree histogram -> dis, fused xd = bf16(dis*x)
__global__ __launch_bounds__(512) void k_degxd(const unsigned* __restrict__ pairs,
                                               const unsigned* __restrict__ bfill,
                                               const float* __restrict__ x,
                                               float* __restrict__ dis,
                                               unsigned* __restrict__ xd, int N) {
    __shared__ unsigned h[NPB];
    int tid = threadIdx.x, b = blockIdx.x;
    h[tid] = 0;
    __syncthreads();
    int r0 = b * CAP;
    int n4 = (int)bfill[b * BPAD] >> 2;
    const uint4* p4 = reinterpret_cast<const uint4*>(pairs + r0);
    for (int i = tid; i < n4; i += 512) {
        uint4 p = p4[i];
        if (p.x != SENT) atomicAdd(&h[p.x & BMSK], 1u);
        if (p.y != SENT) atomicAdd(&h[p.y & BMSK], 1u);
        if (p.z != SENT) atomicAdd(&h[p.z & BMSK], 1u);
        if (p.w != SENT) atomicAdd(&h[p.w & BMSK], 1u);
    }
    __syncthreads();
    int node = (b << BSH) + tid;
    if (node >= N) return;
    float d = rsqrtf((float)(h[tid] + 1u));
    dis[node] = d;
    const float4* xp = reinterpret_cast<const float4*>(x + (size_t)node * F0);
    unsigned pk[8];
#pragma unroll
    for (int q = 0; q < 4; ++q) {
        float4 v = xp[q];
        pk[2 * q + 0] = f2bf(d * v.x) | (f2bf(d * v.y) << 16);
        pk[2 * q + 1] = f2bf(d * v.z) | (f2bf(d * v.w) << 16);
    }
    uint4* o = reinterpret_cast<uint4*>(xd + (size_t)node * 8);
    o[0] = make_uint4(pk[0], pk[1], pk[2], pk[3]);
    o[1] = make_uint4(pk[4], pk[5], pk[6], pk[7]);
}

// per-bucket: LDS f32-atomic aggregation of xd rows, then per-node MLP -> g2
__global__ __launch_bounds__(512) void k_layer1B(const unsigned* __restrict__ pairs,
                                                 const unsigned* __restrict__ bfill,
                                                 const unsigned* __restrict__ xd,
                                                 const float* __restrict__ dis,
                                                 const float* __restrict__ W1,
                                                 const float* __restrict__ b1,
                                                 const float* __restrict__ W2,
                                                 float* __restrict__ g2, int N) {
    __shared__ float y[NPB][17];     // +1 pad: conflict-free node-phase reads
    __shared__ float w1[F0 * F1];
    __shared__ float w2[F1 * F2];
    __shared__ float bb[F1];
    int tid = threadIdx.x, b = blockIdx.x;
    for (int j = tid; j < F0 * F1; j += 512) w1[j] = W1[j];
    for (int j = tid; j < F1 * F2; j += 512) w2[j] = W2[j];
    for (int j = tid; j < F1; j += 512) bb[j] = b1[j];
    float* yf = &y[0][0];
    for (int j = tid; j < NPB * 17; j += 512) yf[j] = 0.0f;
    __syncthreads();
    int r0 = b * CAP;
    int r1 = r0 + (int)bfill[b * BPAD];   // multiple of 16 -> groups never ragged
    int q = tid & 7;
    const unsigned* xq = xd + q;
    for (int i = r0 + tid; i < r1; i += 512) {
        unsigned p = pairs[i];
#pragma unroll
        for (int u = 0; u < 8; ++u) {
            unsigned pu = __shfl(p, u, 8);
            if (pu == SENT) continue;
            unsigned s = pu >> BSH;
            unsigned loc = pu & BMSK;
            unsigned a = xq[(size_t)s * 8];
            atomicAdd(&y[loc][2 * q + 0], bf2f(a & 0xffffu));
            atomicAdd(&y[loc][2 * q + 1], bf2f(a >> 16));
        }
    }
    __syncthreads();
    int node = (b << BSH) + tid;
    if (node >= N) return;
    const uint4* xs = reinterpret_cast<const uint4*>(xd + (size_t)node * 8);
    uint4 s0 = xs[0], s1 = xs[1];
    unsigned su[8] = { s0.x, s0.y, s0.z, s0.w, s1.x, s1.y, s1.z, s1.w };
    float yv[F0];
#pragma unroll
    for (int k = 0; k < 8; ++k) {
        yv[2 * k + 0] = y[tid][2 * k + 0] + bf2f(su[k] & 0xffffu);   // + self loop
        yv[2 * k + 1] = y[tid][2 * k + 1] + bf2f(su[k] >> 16);
    }
    float d = dis[node];
    float p0 = 0.0f, p1 = 0.0f;
#pragma unroll
    for (int j = 0; j < F1; ++j) {
        float s = 0.0f;
#pragma unroll
        for (int k = 0; k < F0; ++k) s = fmaf(yv[k], w1[k * F1 + j], s);
        float r = fmaxf(fmaf(d, s, bb[j]), 0.0f);
        p0 = fmaf(r, w2[j * F2 + 0], p0);
        p1 = fmaf(r, w2[j * F2 + 1], p1);
    }
    *reinterpret_cast<float2*>(g2 + (size_t)node * F2) = make_float2(d * p0, d * p1);
}

// per-bucket: LDS accumulate g2[src] (800KB table, L2-resident) -> out
__global__ __launch_bounds__(512) void k_out2B(const unsigned* __restrict__ pairs,
                                               const unsigned* __restrict__ bfill,
                                               const float* __restrict__ g2,
                                               const float* __restrict__ dis,
                                               const float* __restrict__ b2,
                                               float* __restrict__ out, int N) {
    __shared__ float acc[NPB][2];
    int tid = threadIdx.x, b = blockIdx.x;
    acc[tid][0] = 0.0f;
    acc[tid][1] = 0.0f;
    __syncthreads();
    int r0 = b * CAP;
    int n4 = (int)bfill[b * BPAD] >> 2;
    const uint4* p4 = reinterpret_cast<const uint4*>(pairs + r0);
    for (int i = tid; i < n4; i += 512) {
        uint4 p = p4[i];
        float2 v0, v1, v2, v3;
        bool k0 = p.x != SENT, k1 = p.y != SENT, k2 = p.z != SENT, k3 = p.w != SENT;
        if (k0) v0 = *reinterpret_cast<const float2*>(g2 + (size_t)(p.x >> BSH) * F2);
        if (k1) v1 = *reinterpret_cast<const float2*>(g2 + (size_t)(p.y >> BSH) * F2);
        if (k2) v2 = *reinterpret_cast<const float2*>(g2 + (size_t)(p.z >> BSH) * F2);
        if (k3) v3 = *reinterpret_cast<const float2*>(g2 + (size_t)(p.w >> BSH) * F2);
        if (k0) { atomicAdd(&acc[p.x & BMSK][0], v0.x); atomicAdd(&acc[p.x & BMSK][1], v0.y); }
        if (k1) { atomicAdd(&acc[p.y & BMSK][0], v1.x); atomicAdd(&acc[p.y & BMSK][1], v1.y); }
        if (k2) { atomicAdd(&acc[p.z & BMSK][0], v2.x); atomicAdd(&acc[p.z & BMSK][1], v2.y); }
        if (k3) { atomicAdd(&acc[p.w & BMSK][0], v3.x); atomicAdd(&acc[p.w & BMSK][1], v3.y); }
    }
    __syncthreads();
    int node = (b << BSH) + tid;
    if (node >= N) return;
    float d = dis[node];
    const float2 self = *reinterpret_cast<const float2*>(g2 + (size_t)node * F2);
    out[(size_t)node * F2 + 0] = fmaf(d, acc[tid][0] + self.x, b2[0]);
    out[(size_t)node * F2 + 1] = fmaf(d, acc[tid][1] + self.y, b2[1]);
}

extern "C" void kernel_launch(void* const* d_in, const int* in_sizes, int n_in,
                              void* d_out, int out_size, void* d_ws, size_t ws_size,
                              hipStream_t stream) {
    const float* x  = (const float*)d_in[0];
    const int* ei   = (const int*)d_in[1];
    const float* W1 = (const float*)d_in[2];
    const float* b1 = (const float*)d_in[3];
    const float* W2 = (const float*)d_in[4];
    const float* b2 = (const float*)d_in[5];
    float* out = (float*)d_out;

    const int N = in_sizes[0] / F0;          // 100000
    const int E = in_sizes[1] / 2;           // 3200000
    const int* src = ei;
    const int* dst = ei + E;
    const int nb = (N + BMSK) >> BSH;        // 196 buckets of 512 nodes
    const int nchunk = (E + EPB - 1) / EPB;  // 391 chunks

    // workspace layout (u32 units); pairs 16B-aligned (offset 4096 u32)
    unsigned* bfill = (unsigned*)d_ws;                    // MAXNB*BPAD
    unsigned* pairs = bfill + MAXNB * BPAD;               // nb*CAP (~19.3MB)
    unsigned* xd    = pairs + (size_t)nb * CAP;           // 8N (32B rows)
    float* dis      = (float*)(xd + (size_t)8 * N);       // N
    float* g2       = dis + N;                            // 2N
    // total ~ 23.7 MB

    hipMemsetAsync(bfill, 0, (size_t)MAXNB * BPAD * sizeof(unsigned), stream);

    k_binA<<<nchunk, 512, 0, stream>>>(src, dst, bfill, pairs, E, nb);
    k_degxd<<<nb, 512, 0, stream>>>(pairs, bfill, x, dis, xd, N);
    k_layer1B<<<nb, 512, 0, stream>>>(pairs, bfill, xd, dis, W1, b1, W2, g2, N);
    k_out2B<<<nb, 512, 0, stream>>>(pairs, bfill, g2, dis, b2, out, N);
}

// Round 11
// 119.330 us; speedup vs baseline: 3.6876x; 3.6876x over previous
//
#include <hip/hip_runtime.h>

// GCN 2-layer, 5 dispatches (incl. 16KB memset):
//   binA: chunk-wise LDS counting sort of edges by dst-bucket (512 nodes),
//         64B-aligned reservations into FIXED per-bucket regions (b*CAP)
//   binB: per-bucket node hist + scan -> cnt/dis/rstart + xd=bf16(dis*x),
//         then node-sorted scatter of src into esrc (fixed region b*CAP)
//   layer1: per-node 8-lane gather-aggregate of xd rows (32B, L2-resident)
//         then in-register MLP (W1,b1,relu,W2) -> g2            [linearity]
//   out2: per-node 4-lane gather-aggregate of g2 -> out
// norm trick: g = dis*(h@W); out[v] = dis[v]*(sum_{u->v} g[u] + g[v]) + b.

static constexpr int F0 = 16;
static constexpr int F1 = 32;
static constexpr int F2 = 2;
static constexpr int BSH  = 9;      // bucket = dst>>9 (512 nodes)
static constexpr int BMSK = 511;
static constexpr int NPB  = 512;    // nodes per bucket
static constexpr int MAXNB = 256;   // max buckets (N <= 131072)
static constexpr int BPAD  = 16;    // cursor padded to own 64B line
static constexpr int EPB   = 8192;  // edges per binA chunk
static constexpr int CAP   = 24576; // slots per bucket region (exp ~19.3k)
static constexpr int SORTCAP = EPB + MAXNB * 16;   // 12288
static constexpr unsigned SENT = 0xFFFFFFFFu;

__device__ inline unsigned roundup16(unsigned h) { return (h + 15u) & ~15u; }

__device__ inline unsigned f2bf(float f) {
    unsigned u = __float_as_uint(f);
    return (u + 0x7fffu + ((u >> 16) & 1u)) >> 16;   // RNE
}
__device__ inline float bf2f(unsigned b) {
    return __uint_as_float(b << 16);
}

// LDS counting sort of a chunk, then per-bucket wave burst copy to global.
__global__ __launch_bounds__(512) void k_binA(const int* __restrict__ src,
                                              const int* __restrict__ dst,
                                              unsigned* __restrict__ bfill,
                                              unsigned* __restrict__ pairs,
                                              int E, int nb) {
    __shared__ unsigned h[MAXNB];
    __shared__ unsigned lbase[MAXNB];
    __shared__ unsigned bs[MAXNB];
    __shared__ unsigned cur[MAXNB];
    __shared__ __attribute__((aligned(16))) unsigned sorted[SORTCAP];
    int tid = threadIdx.x;
    for (int b = tid; b < MAXNB; b += 512) { h[b] = 0; cur[b] = 0; }
    for (int i = tid; i < SORTCAP; i += 512) sorted[i] = SENT;
    __syncthreads();
    int e0 = blockIdx.x * EPB;
    int e1 = min(e0 + EPB, E);
    for (int e = e0 + tid; e < e1; e += 512)
        atomicAdd(&h[((unsigned)dst[e]) >> BSH], 1u);
    __syncthreads();
    if (tid < MAXNB) lbase[tid] = roundup16(h[tid]);
    __syncthreads();
    for (int off = 1; off < MAXNB; off <<= 1) {
        unsigned t = (tid >= off && tid < MAXNB) ? lbase[tid - off] : 0u;
        __syncthreads();
        if (tid < MAXNB) lbase[tid] += t;
        __syncthreads();
    }
    if (tid < MAXNB) lbase[tid] -= roundup16(h[tid]);   // exclusive
    if (tid < nb && h[tid])
        bs[tid] = (unsigned)(tid * CAP) + atomicAdd(&bfill[tid * BPAD], roundup16(h[tid]));
    __syncthreads();
    for (int e = e0 + tid; e < e1; e += 512) {
        unsigned d = (unsigned)dst[e];
        unsigned b = d >> BSH;
        unsigned pos = lbase[b] + atomicAdd(&cur[b], 1u);
        sorted[pos] = (((unsigned)src[e]) << BSH) | (d & BMSK);
    }
    __syncthreads();
    int wid = tid >> 6;
    int lane = tid & 63;
    for (int b = wid; b < nb; b += 8) {
        unsigned np = roundup16(h[b]) >> 2;   // uint4 count
        if (!np) continue;
        const uint4* sp = reinterpret_cast<const uint4*>(&sorted[lbase[b]]);
        uint4* gp = reinterpret_cast<uint4*>(&pairs[bs[b]]);
        for (unsigned k = lane; k < np; k += 64) gp[k] = sp[k];
    }
}

// per-bucket: node hist + scan -> cnt/dis/rstart + xd, node-sorted esrc scatter
__global__ __launch_bounds__(512) void k_binB(const unsigned* __restrict__ pairs,
                                              const unsigned* __restrict__ bfill,
                                              const float* __restrict__ x,
                                              int* __restrict__ cnt, float* __restrict__ dis,
                                              int* __restrict__ rstart, int* __restrict__ esrc,
                                              unsigned* __restrict__ xd, int N) {
    __shared__ unsigned h[NPB];
    __shared__ int sc[NPB];
    __shared__ unsigned cur[NPB];
    int tid = threadIdx.x, b = blockIdx.x;
    h[tid] = 0;
    cur[tid] = 0;
    __syncthreads();
    int r0 = b * CAP;
    int r1 = r0 + (int)bfill[b * BPAD];
    for (int i = r0 + tid; i < r1; i += 512) {
        unsigned p = pairs[i];
        if (p != SENT) atomicAdd(&h[p & BMSK], 1u);
    }
    __syncthreads();
    int v = (int)h[tid];
    sc[tid] = v;
    __syncthreads();
    for (int off = 1; off < NPB; off <<= 1) {
        int t = (tid >= off) ? sc[tid - off] : 0;
        __syncthreads();
        sc[tid] += t;
        __syncthreads();
    }
    int ex = sc[tid] - v;
    __syncthreads();
    sc[tid] = ex;
    __syncthreads();
    int node = (b << BSH) + tid;
    if (node < N) {
        float d = rsqrtf((float)(v + 1));
        cnt[node] = v;
        dis[node] = d;
        rstart[node] = r0 + ex;
        const float4* xp = reinterpret_cast<const float4*>(x + (size_t)node * F0);
        unsigned pk[8];
#pragma unroll
        for (int q = 0; q < 4; ++q) {
            float4 vv = xp[q];
            pk[2 * q + 0] = f2bf(d * vv.x) | (f2bf(d * vv.y) << 16);
            pk[2 * q + 1] = f2bf(d * vv.z) | (f2bf(d * vv.w) << 16);
        }
        uint4* o = reinterpret_cast<uint4*>(xd + (size_t)node * 8);
        o[0] = make_uint4(pk[0], pk[1], pk[2], pk[3]);
        o[1] = make_uint4(pk[4], pk[5], pk[6], pk[7]);
    }
    for (int i = r0 + tid; i < r1; i += 512) {
        unsigned p = pairs[i];
        if (p == SENT) continue;
        unsigned l = p & BMSK;
        unsigned off = atomicAdd(&cur[l], 1u);
        esrc[r0 + sc[l] + (int)off] = (int)(p >> BSH);
    }
}

// fused layer1: 8 lanes/node gather-aggregate xd (1 u32/lane = 32B/row),
// then y exchange via wave-local LDS and in-register MLP -> g2
__global__ void k_layer1(const unsigned* __restrict__ xd, const int* __restrict__ cnt,
                         const int* __restrict__ rstart, const int* __restrict__ esrc,
                         const float* __restrict__ dis, const float* __restrict__ b1,
                         const float* __restrict__ W1, const float* __restrict__ W2,
                         float* __restrict__ g2, int N) {
    __shared__ float w1[F0 * F1];
    __shared__ float w2[F1 * F2];
    __shared__ float bb[F1];
    __shared__ float ymat[32][17];   // 32 nodes/block, +1 pad
    for (int j = threadIdx.x; j < F0 * F1; j += blockDim.x) w1[j] = W1[j];
    for (int j = threadIdx.x; j < F1 * F2; j += blockDim.x) w2[j] = W2[j];
    for (int j = threadIdx.x; j < F1; j += blockDim.x) bb[j] = b1[j];
    __syncthreads();
    int t = blockIdx.x * blockDim.x + threadIdx.x;
    int v = t >> 3;
    int q = t & 7;
    if (v >= N) return;
    const unsigned* base = xd + q;             // row stride 8 u32
    unsigned sw = base[(size_t)v * 8];         // self loop xd[v]
    float a0 = bf2f(sw & 0xffffu);
    float a1 = bf2f(sw >> 16);
    int beg = rstart[v];
    int n = cnt[v];
    int n8 = n & ~7;
    for (int j = 0; j < n8; j += 8) {
        int idx = esrc[beg + j + q];           // 8 distinct edges across group
#pragma unroll
        for (int u = 0; u < 8; ++u) {
            int s = __shfl(idx, u, 8);
            unsigned a = base[(size_t)s * 8];
            a0 += bf2f(a & 0xffffu);
            a1 += bf2f(a >> 16);
        }
    }
    for (int j = n8; j < n; ++j) {             // tail: uniform load
        int s = esrc[beg + j];
        unsigned a = base[(size_t)s * 8];
        a0 += bf2f(a & 0xffffu);
        a1 += bf2f(a >> 16);
    }
    // exchange y within the 8-lane group (wave-local LDS, lockstep)
    int ln = threadIdx.x >> 3;
    ymat[ln][2 * q + 0] = a0;
    ymat[ln][2 * q + 1] = a1;
    float y[F0];
#pragma unroll
    for (int k = 0; k < F0; ++k) y[k] = ymat[ln][k];
    float d = dis[v];
    float p0 = 0.0f, p1 = 0.0f;
#pragma unroll
    for (int u = 0; u < 4; ++u) {
        int jf = q * 4 + u;                    // 32 features across 8 lanes x 4
        float s = 0.0f;
#pragma unroll
        for (int k = 0; k < F0; ++k) s = fmaf(y[k], w1[k * F1 + jf], s);
        float r = fmaxf(fmaf(d, s, bb[jf]), 0.0f);
        p0 = fmaf(r, w2[jf * F2 + 0], p0);
        p1 = fmaf(r, w2[jf * F2 + 1], p1);
    }
#pragma unroll
    for (int off = 1; off < 8; off <<= 1) {
        p0 += __shfl_xor(p0, off);
        p1 += __shfl_xor(p1, off);
    }
    if (q == 0) {
        g2[(size_t)v * F2 + 0] = d * p0;
        g2[(size_t)v * F2 + 1] = d * p1;
    }
}

// fused layer2 aggregate + output: 4 lanes per node, strided edges, 4x unroll
__global__ void k_out2(const float* __restrict__ g2, const int* __restrict__ cnt,
                       const int* __restrict__ rstart, const int* __restrict__ esrc,
                       const float* __restrict__ dis, const float* __restrict__ b2,
                       float* __restrict__ out, int N) {
    int t = blockIdx.x * blockDim.x + threadIdx.x;
    int v = t >> 2;
    int l = t & 3;
    if (v >= N) return;
    float o0 = 0.0f, o1 = 0.0f;
    int beg = rstart[v];
    int end = beg + cnt[v];
    int j = beg + l;
    for (; j + 12 < end; j += 16) {        // 4 independent gathers in flight
        int s0 = esrc[j];
        int s1 = esrc[j + 4];
        int s2 = esrc[j + 8];
        int s3 = esrc[j + 12];
        float2 a0 = *reinterpret_cast<const float2*>(g2 + (size_t)s0 * F2);
        float2 a1 = *reinterpret_cast<const float2*>(g2 + (size_t)s1 * F2);
        float2 a2 = *reinterpret_cast<const float2*>(g2 + (size_t)s2 * F2);
        float2 a3 = *reinterpret_cast<const float2*>(g2 + (size_t)s3 * F2);
        o0 += a0.x + a1.x + a2.x + a3.x;
        o1 += a0.y + a1.y + a2.y + a3.y;
    }
    for (; j < end; j += 4) {
        int s = esrc[j];
        const float2 a = *reinterpret_cast<const float2*>(g2 + (size_t)s * F2);
        o0 += a.x; o1 += a.y;
    }
#pragma unroll
    for (int off = 1; off < 4; off <<= 1) {
        o0 += __shfl_xor(o0, off);
        o1 += __shfl_xor(o1, off);
    }
    if (l == 0) {
        float d = dis[v];
        const float2 self = *reinterpret_cast<const float2*>(g2 + (size_t)v * F2);
        out[(size_t)v * F2 + 0] = fmaf(d, o0 + self.x, b2[0]);
        out[(size_t)v * F2 + 1] = fmaf(d, o1 + self.y, b2[1]);
    }
}

extern "C" void kernel_launch(void* const* d_in, const int* in_sizes, int n_in,
                              void* d_out, int out_size, void* d_ws, size_t ws_size,
                              hipStream_t stream) {
    const float* x  = (const float*)d_in[0];
    const int* ei   = (const int*)d_in[1];
    const float* W1 = (const float*)d_in[2];
    const float* b1 = (const float*)d_in[3];
    const float* W2 = (const float*)d_in[4];
    const float* b2 = (const float*)d_in[5];
    float* out = (float*)d_out;

    const int N = in_sizes[0] / F0;          // 100000
    const int E = in_sizes[1] / 2;           // 3200000
    const int* src = ei;
    const int* dst = ei + E;
    const int nb = (N + BMSK) >> BSH;        // 196 buckets of 512 nodes
    const int nchunk = (E + EPB - 1) / EPB;  // 391 chunks

    // workspace layout (u32 units); pairs 16B-aligned
    unsigned* bfill = (unsigned*)d_ws;                    // MAXNB*BPAD (16KB)
    unsigned* pairs = bfill + MAXNB * BPAD;               // nb*CAP (~19.3MB)
    int* esrc       = (int*)(pairs + (size_t)nb * CAP);   // nb*CAP (~19.3MB)
    unsigned* xd    = (unsigned*)(esrc + (size_t)nb * CAP); // 8N (32B rows)
    float* dis      = (float*)(xd + (size_t)8 * N);       // N
    int* cnt        = (int*)(dis + N);                    // N
    int* rstart     = cnt + N;                            // N
    float* g2       = (float*)(rstart + N);               // 2N
    // total ~ 44 MB

    hipMemsetAsync(bfill, 0, (size_t)MAXNB * BPAD * sizeof(unsigned), stream);

    const int B = 256;
    k_binA<<<nchunk, 512, 0, stream>>>(src, dst, bfill, pairs, E, nb);
    k_binB<<<nb, 512, 0, stream>>>(pairs, bfill, x, cnt, dis, rstart, esrc, xd, N);
    k_layer1<<<(N * 8 + B - 1) / B, B, 0, stream>>>(xd, cnt, rstart, esrc, dis, b1, W1, W2, g2, N);
    k_out2<<<(N * 4 + B - 1) / B, B, 0, stream>>>(g2, cnt, rstart, esrc, dis, b2, out, N);
}

// Round 12
// 105.983 us; speedup vs baseline: 4.1520x; 1.1259x over previous
//
#include <hip/hip_runtime.h>

// GCN 2-layer, 5 dispatches (incl. 16KB memset):
//   binA: chunk-wise LDS counting sort of edges by dst-bucket (512 nodes),
//         register-stashed edges (single global read), 64B-aligned
//         reservations into FIXED per-bucket regions (b*CAP)
//   binB: per-bucket node hist + wave-scan -> cnt/dis/rstart + xd=bf16(dis*x),
//         then node-sorted scatter of src into esrc (fixed region b*CAP)
//   layer1: per-node 8-lane gather-aggregate of xd rows (32B, L2-resident)
//         then in-register MLP (W1,b1,relu,W2) -> g2            [linearity]
//   out2: per-node 4-lane gather-aggregate of g2 -> out
// norm trick: g = dis*(h@W); out[v] = dis[v]*(sum_{u->v} g[u] + g[v]) + b.

static constexpr int F0 = 16;
static constexpr int F1 = 32;
static constexpr int F2 = 2;
static constexpr int BSH  = 9;      // bucket = dst>>9 (512 nodes)
static constexpr int BMSK = 511;
static constexpr int NPB  = 512;    // nodes per bucket
static constexpr int MAXNB = 256;   // max buckets (N <= 131072)
static constexpr int BPAD  = 16;    // cursor padded to own 64B line
static constexpr int EPB   = 8192;  // edges per binA chunk (= 16 per thread)
static constexpr int CAP   = 24576; // slots per bucket region (exp ~19.3k)
static constexpr int SORTCAP = EPB + MAXNB * 16;   // 12288
static constexpr unsigned SENT = 0xFFFFFFFFu;

__device__ inline unsigned roundup16(unsigned h) { return (h + 15u) & ~15u; }

__device__ inline unsigned f2bf(float f) {
    unsigned u = __float_as_uint(f);
    return (u + 0x7fffu + ((u >> 16) & 1u)) >> 16;   // RNE
}
__device__ inline float bf2f(unsigned b) {
    return __uint_as_float(b << 16);
}

// LDS counting sort of a chunk (edges stashed in registers; one global read),
// then per-bucket wave burst copy to global.
__global__ __launch_bounds__(512) void k_binA(const int* __restrict__ src,
                                              const int* __restrict__ dst,
                                              unsigned* __restrict__ bfill,
                                              unsigned* __restrict__ pairs,
                                              int E, int nb) {
    __shared__ unsigned h[MAXNB];
    __shared__ unsigned lbase[MAXNB];
    __shared__ unsigned bs_[MAXNB];
    __shared__ unsigned cur[MAXNB];
    __shared__ unsigned wsum[8];
    __shared__ unsigned wbase[8];
    __shared__ __attribute__((aligned(16))) unsigned sorted[SORTCAP];
    int tid = threadIdx.x;
    for (int b = tid; b < MAXNB; b += 512) { h[b] = 0; cur[b] = 0; }
    if (tid < 8) wsum[tid] = 0;
    __syncthreads();
    int e0 = blockIdx.x * EPB;
    int cn = min(EPB, E - e0);
    unsigned key[16];
    unsigned bkt[16];
#pragma unroll
    for (int j = 0; j < 16; ++j) {
        int idx = j * 512 + tid;
        if (idx < cn) {
            unsigned d = (unsigned)dst[e0 + idx];
            unsigned s = (unsigned)src[e0 + idx];
            unsigned b = d >> BSH;
            key[j] = (s << BSH) | (d & BMSK);
            bkt[j] = b;
            atomicAdd(&h[b], 1u);
        }
    }
    __syncthreads();
    // exclusive scan of roundup16(h) over 256 entries: wave shfl scan, 2 barriers
    unsigned pv = 0, px = 0;
    if (tid < MAXNB) {
        pv = roundup16(h[tid]);
        px = pv;
#pragma unroll
        for (int off = 1; off < 64; off <<= 1) {
            unsigned t = __shfl_up(px, off, 64);
            if ((tid & 63) >= off) px += t;
        }
        if ((tid & 63) == 63) wsum[tid >> 6] = px;
    }
    __syncthreads();
    if (tid < 8) {
        unsigned acc = 0;
        for (int k = 0; k < tid; ++k) acc += wsum[k];
        wbase[tid] = acc;
    }
    __syncthreads();
    if (tid < MAXNB) {
        unsigned ex = px - pv + wbase[tid >> 6];
        lbase[tid] = ex;
        if (tid < nb && h[tid])
            bs_[tid] = (unsigned)(tid * CAP) + atomicAdd(&bfill[tid * BPAD], roundup16(h[tid]));
    }
    __syncthreads();
    // scatter from registers into LDS (node-agnostic, bucket-sorted)
#pragma unroll
    for (int j = 0; j < 16; ++j) {
        int idx = j * 512 + tid;
        if (idx < cn) {
            unsigned b = bkt[j];
            unsigned pos = lbase[b] + atomicAdd(&cur[b], 1u);
            sorted[pos] = key[j];
        }
    }
    // sentinel-fill ONLY the pad slots (disjoint from scatter range)
    for (int b = tid; b < nb; b += 512) {
        unsigned hb = h[b];
        if (!hb) continue;
        unsigned k0 = lbase[b] + hb;
        unsigned k1 = lbase[b] + roundup16(hb);
        for (unsigned k = k0; k < k1; ++k) sorted[k] = SENT;
    }
    __syncthreads();
    // burst copy: one wave per bucket, uint4 contiguous stores
    int wid = tid >> 6;
    int lane = tid & 63;
    for (int b = wid; b < nb; b += 8) {
        unsigned np = roundup16(h[b]) >> 2;   // uint4 count
        if (!np) continue;
        const uint4* sp = reinterpret_cast<const uint4*>(&sorted[lbase[b]]);
        uint4* gp = reinterpret_cast<uint4*>(&pairs[bs_[b]]);
        for (unsigned k = lane; k < np; k += 64) gp[k] = sp[k];
    }
}

// per-bucket: node hist (uint4 pass) + wave scan -> cnt/dis/rstart + xd,
// node-sorted scatter (uint4 pass) of src into esrc
__global__ __launch_bounds__(512) void k_binB(const unsigned* __restrict__ pairs,
                                              const unsigned* __restrict__ bfill,
                                              const float* __restrict__ x,
                                              int* __restrict__ cnt, float* __restrict__ dis,
                                              int* __restrict__ rstart, int* __restrict__ esrc,
                                              unsigned* __restrict__ xd, int N) {
    __shared__ unsigned h[NPB];
    __shared__ unsigned sc_[NPB];
    __shared__ unsigned cur[NPB];
    __shared__ unsigned wsum[8];
    __shared__ unsigned wbase[8];
    int tid = threadIdx.x, b = blockIdx.x;
    h[tid] = 0;
    cur[tid] = 0;
    __syncthreads();
    int r0 = b * CAP;
    int n4 = (int)bfill[b * BPAD] >> 2;
    const uint4* p4 = reinterpret_cast<const uint4*>(pairs + r0);
    for (int i = tid; i < n4; i += 512) {
        uint4 p = p4[i];
        if (p.x != SENT) atomicAdd(&h[p.x & BMSK], 1u);
        if (p.y != SENT) atomicAdd(&h[p.y & BMSK], 1u);
        if (p.z != SENT) atomicAdd(&h[p.z & BMSK], 1u);
        if (p.w != SENT) atomicAdd(&h[p.w & BMSK], 1u);
    }
    __syncthreads();
    // exclusive scan over 512 entries: wave shfl scan, 2 barriers
    unsigned v = h[tid];
    unsigned x2 = v;
#pragma unroll
    for (int off = 1; off < 64; off <<= 1) {
        unsigned t = __shfl_up(x2, off, 64);
        if ((tid & 63) >= off) x2 += t;
    }
    if ((tid & 63) == 63) wsum[tid >> 6] = x2;
    __syncthreads();
    if (tid < 8) {
        unsigned acc = 0;
        for (int k = 0; k < tid; ++k) acc += wsum[k];
        wbase[tid] = acc;
    }
    __syncthreads();
    unsigned ex = x2 - v + wbase[tid >> 6];
    sc_[tid] = ex;
    int node = (b << BSH) + tid;
    if (node < N) {
        float d = rsqrtf((float)(v + 1));
        cnt[node] = (int)v;
        dis[node] = d;
        rstart[node] = r0 + (int)ex;
        const float4* xp = reinterpret_cast<const float4*>(x + (size_t)node * F0);
        unsigned pk[8];
#pragma unroll
        for (int q = 0; q < 4; ++q) {
            float4 vv = xp[q];
            pk[2 * q + 0] = f2bf(d * vv.x) | (f2bf(d * vv.y) << 16);
            pk[2 * q + 1] = f2bf(d * vv.z) | (f2bf(d * vv.w) << 16);
        }
        uint4* o = reinterpret_cast<uint4*>(xd + (size_t)node * 8);
        o[0] = make_uint4(pk[0], pk[1], pk[2], pk[3]);
        o[1] = make_uint4(pk[4], pk[5], pk[6], pk[7]);
    }
    // no barrier needed: cur[] zeroed before first barrier; sc_ written by owner
    __syncthreads();
    for (int i = tid; i < n4; i += 512) {
        uint4 p = p4[i];
        if (p.x != SENT) { unsigned l = p.x & BMSK; unsigned o_ = atomicAdd(&cur[l], 1u); esrc[r0 + sc_[l] + o_] = (int)(p.x >> BSH); }
        if (p.y != SENT) { unsigned l = p.y & BMSK; unsigned o_ = atomicAdd(&cur[l], 1u); esrc[r0 + sc_[l] + o_] = (int)(p.y >> BSH); }
        if (p.z != SENT) { unsigned l = p.z & BMSK; unsigned o_ = atomicAdd(&cur[l], 1u); esrc[r0 + sc_[l] + o_] = (int)(p.z >> BSH); }
        if (p.w != SENT) { unsigned l = p.w & BMSK; unsigned o_ = atomicAdd(&cur[l], 1u); esrc[r0 + sc_[l] + o_] = (int)(p.w >> BSH); }
    }
}

// fused layer1: 8 lanes/node gather-aggregate xd (1 u32/lane = 32B/row),
// then y exchange via wave-local LDS and in-register MLP -> g2
__global__ void k_layer1(const unsigned* __restrict__ xd, const int* __restrict__ cnt,
                         const int* __restrict__ rstart, const int* __restrict__ esrc,
                         const float* __restrict__ dis, const float* __restrict__ b1,
                         const float* __restrict__ W1, const float* __restrict__ W2,
                         float* __restrict__ g2, int N) {
    __shared__ float w1[F0 * F1];
    __shared__ float w2[F1 * F2];
    __shared__ float bb[F1];
    __shared__ float ymat[32][17];   // 32 nodes/block, +1 pad
    for (int j = threadIdx.x; j < F0 * F1; j += blockDim.x) w1[j] = W1[j];
    for (int j = threadIdx.x; j < F1 * F2; j += blockDim.x) w2[j] = W2[j];
    for (int j = threadIdx.x; j < F1; j += blockDim.x) bb[j] = b1[j];
    __syncthreads();
    int t = blockIdx.x * blockDim.x + threadIdx.x;
    int v = t >> 3;
    int q = t & 7;
    if (v >= N) return;
    const unsigned* base = xd + q;             // row stride 8 u32
    unsigned sw = base[(size_t)v * 8];         // self loop xd[v]
    float a0 = bf2f(sw & 0xffffu);
    float a1 = bf2f(sw >> 16);
    int beg = rstart[v];
    int n = cnt[v];
    int n8 = n & ~7;
    for (int j = 0; j < n8; j += 8) {
        int idx = esrc[beg + j + q];           // 8 distinct edges across group
#pragma unroll
        for (int u = 0; u < 8; ++u) {
            int s = __shfl(idx, u, 8);
            unsigned a = base[(size_t)s * 8];
            a0 += bf2f(a & 0xffffu);
            a1 += bf2f(a >> 16);
        }
    }
    for (int j = n8; j < n; ++j) {             // tail: uniform load
        int s = esrc[beg + j];
        unsigned a = base[(size_t)s * 8];
        a0 += bf2f(a & 0xffffu);
        a1 += bf2f(a >> 16);
    }
    // exchange y within the 8-lane group (wave-local LDS, lockstep)
    int ln = threadIdx.x >> 3;
    ymat[ln][2 * q + 0] = a0;
    ymat[ln][2 * q + 1] = a1;
    float y[F0];
#pragma unroll
    for (int k = 0; k < F0; ++k) y[k] = ymat[ln][k];
    float d = dis[v];
    float p0 = 0.0f, p1 = 0.0f;
#pragma unroll
    for (int u = 0; u < 4; ++u) {
        int jf = q * 4 + u;                    // 32 features across 8 lanes x 4
        float s = 0.0f;
#pragma unroll
        for (int k = 0; k < F0; ++k) s = fmaf(y[k], w1[k * F1 + jf], s);
        float r = fmaxf(fmaf(d, s, bb[jf]), 0.0f);
        p0 = fmaf(r, w2[jf * F2 + 0], p0);
        p1 = fmaf(r, w2[jf * F2 + 1], p1);
    }
#pragma unroll
    for (int off = 1; off < 8; off <<= 1) {
        p0 += __shfl_xor(p0, off);
        p1 += __shfl_xor(p1, off);
    }
    if (q == 0) {
        g2[(size_t)v * F2 + 0] = d * p0;
        g2[(size_t)v * F2 + 1] = d * p1;
    }
}

// fused layer2 aggregate + output: 4 lanes per node, strided edges, 4x unroll
__global__ void k_out2(const float* __restrict__ g2, const int* __restrict__ cnt,
                       const int* __restrict__ rstart, const int* __restrict__ esrc,
                       const float* __restrict__ dis, const float* __restrict__ b2,
                       float* __restrict__ out, int N) {
    int t = blockIdx.x * blockDim.x + threadIdx.x;
    int v = t >> 2;
    int l = t & 3;
    if (v >= N) return;
    float o0 = 0.0f, o1 = 0.0f;
    int beg = rstart[v];
    int end = beg + cnt[v];
    int j = beg + l;
    for (; j + 12 < end; j += 16) {        // 4 independent gathers in flight
        int s0 = esrc[j];
        int s1 = esrc[j + 4];
        int s2 = esrc[j + 8];
        int s3 = esrc[j + 12];
        float2 a0 = *reinterpret_cast<const float2*>(g2 + (size_t)s0 * F2);
        float2 a1 = *reinterpret_cast<const float2*>(g2 + (size_t)s1 * F2);
        float2 a2 = *reinterpret_cast<const float2*>(g2 + (size_t)s2 * F2);
        float2 a3 = *reinterpret_cast<const float2*>(g2 + (size_t)s3 * F2);
        o0 += a0.x + a1.x + a2.x + a3.x;
        o1 += a0.y + a1.y + a2.y + a3.y;
    }
    for (; j < end; j += 4) {
        int s = esrc[j];
        const float2 a = *reinterpret_cast<const float2*>(g2 + (size_t)s * F2);
        o0 += a.x; o1 += a.y;
    }
#pragma unroll
    for (int off = 1; off < 4; off <<= 1) {
        o0 += __shfl_xor(o0, off);
        o1 += __shfl_xor(o1, off);
    }
    if (l == 0) {
        float d = dis[v];
        const float2 self = *reinterpret_cast<const float2*>(g2 + (size_t)v * F2);
        out[(size_t)v * F2 + 0] = fmaf(d, o0 + self.x, b2[0]);
        out[(size_t)v * F2 + 1] = fmaf(d, o1 + self.y, b2[1]);
    }
}

extern "C" void kernel_launch(void* const* d_in, const int* in_sizes, int n_in,
                              void* d_out, int out_size, void* d_ws, size_t ws_size,
                              hipStream_t stream) {
    const float* x  = (const float*)d_in[0];
    const int* ei   = (const int*)d_in[1];
    const float* W1 = (const float*)d_in[2];
    const float* b1 = (const float*)d_in[3];
    const float* W2 = (const float*)d_in[4];
    const float* b2 = (const float*)d_in[5];
    float* out = (float*)d_out;

    const int N = in_sizes[0] / F0;          // 100000
    const int E = in_sizes[1] / 2;           // 3200000
    const int* src = ei;
    const int* dst = ei + E;
    const int nb = (N + BMSK) >> BSH;        // 196 buckets of 512 nodes
    const int nchunk = (E + EPB - 1) / EPB;  // 391 chunks

    // workspace layout (u32 units); pairs 16B-aligned
    unsigned* bfill = (unsigned*)d_ws;                    // MAXNB*BPAD (16KB)
    unsigned* pairs = bfill + MAXNB * BPAD;               // nb*CAP (~19.3MB)
    int* esrc       = (int*)(pairs + (size_t)nb * CAP);   // nb*CAP (~19.3MB)
    unsigned* xd    = (unsigned*)(esrc + (size_t)nb * CAP); // 8N (32B rows)
    float* dis      = (float*)(xd + (size_t)8 * N);       // N
    int* cnt        = (int*)(dis + N);                    // N
    int* rstart     = cnt + N;                            // N
    float* g2       = (float*)(rstart + N);               // 2N
    // total ~ 44 MB

    hipMemsetAsync(bfill, 0, (size_t)MAXNB * BPAD * sizeof(unsigned), stream);

    const int B = 256;
    k_binA<<<nchunk, 512, 0, stream>>>(src, dst, bfill, pairs, E, nb);
    k_binB<<<nb, 512, 0, stream>>>(pairs, bfill, x, cnt, dis, rstart, esrc, xd, N);
    k_layer1<<<(N * 8 + B - 1) / B, B, 0, stream>>>(xd, cnt, rstart, esrc, dis, b1, W1, W2, g2, N);
    k_out2<<<(N * 4 + B - 1) / B, B, 0, stream>>>(g2, cnt, rstart, esrc, dis, b2, out, N);
}

// Round 13
// 105.268 us; speedup vs baseline: 4.1802x; 1.0068x over previous
//
#include <hip/hip_runtime.h>

// GCN 2-layer, 5 dispatches:
//   zero: 16KB cursor clear (own kernel; hipMemsetAsync's fill kernel measured
//         ~41us for 16KB -> replaced)
//   binA: chunk-wise LDS counting sort of edges by dst-bucket (512 nodes),
//         register-stashed edges (single global read), 64B-aligned
//         reservations into FIXED per-bucket regions (b*CAP)
//   binB: per-bucket node hist + wave-scan -> cnt/dis/rstart + xd=bf16(dis*x),
//         then node-sorted scatter of src into esrc (fixed region b*CAP)
//   layer1: per-node 8-lane gather-aggregate of xd rows (32B, L2-resident)
//         then in-register MLP (W1,b1,relu,W2) -> g2            [linearity]
//   out2: per-node 4-lane gather-aggregate of g2 -> out
// norm trick: g = dis*(h@W); out[v] = dis[v]*(sum_{u->v} g[u] + g[v]) + b.

static constexpr int F0 = 16;
static constexpr int F1 = 32;
static constexpr int F2 = 2;
static constexpr int BSH  = 9;      // bucket = dst>>9 (512 nodes)
static constexpr int BMSK = 511;
static constexpr int NPB  = 512;    // nodes per bucket
static constexpr int MAXNB = 256;   // max buckets (N <= 131072)
static constexpr int BPAD  = 16;    // cursor padded to own 64B line
static constexpr int EPB   = 8192;  // edges per binA chunk (= 16 per thread)
static constexpr int CAP   = 24576; // slots per bucket region (exp ~19.3k)
static constexpr int SORTCAP = EPB + MAXNB * 16;   // 12288
static constexpr unsigned SENT = 0xFFFFFFFFu;

__device__ inline unsigned roundup16(unsigned h) { return (h + 15u) & ~15u; }

__device__ inline unsigned f2bf(float f) {
    unsigned u = __float_as_uint(f);
    return (u + 0x7fffu + ((u >> 16) & 1u)) >> 16;   // RNE
}
__device__ inline float bf2f(unsigned b) {
    return __uint_as_float(b << 16);
}

// zero the 4096-word cursor array (16KB) — replaces pathological rocclr fill
__global__ void k_zero(unsigned* __restrict__ p) {
    p[blockIdx.x * 256 + threadIdx.x] = 0u;
}

// LDS counting sort of a chunk (edges stashed in registers; one global read),
// then per-bucket wave burst copy to global.
__global__ __launch_bounds__(512) void k_binA(const int* __restrict__ src,
                                              const int* __restrict__ dst,
                                              unsigned* __restrict__ bfill,
                                              unsigned* __restrict__ pairs,
                                              int E, int nb) {
    __shared__ unsigned h[MAXNB];
    __shared__ unsigned lbase[MAXNB];
    __shared__ unsigned bs_[MAXNB];
    __shared__ unsigned cur[MAXNB];
    __shared__ unsigned wsum[8];
    __shared__ unsigned wbase[8];
    __shared__ __attribute__((aligned(16))) unsigned sorted[SORTCAP];
    int tid = threadIdx.x;
    for (int b = tid; b < MAXNB; b += 512) { h[b] = 0; cur[b] = 0; }
    if (tid < 8) wsum[tid] = 0;
    __syncthreads();
    int e0 = blockIdx.x * EPB;
    int cn = min(EPB, E - e0);
    unsigned key[16];
    unsigned bkt[16];
#pragma unroll
    for (int j = 0; j < 16; ++j) {
        int idx = j * 512 + tid;
        if (idx < cn) {
            unsigned d = (unsigned)dst[e0 + idx];
            unsigned s = (unsigned)src[e0 + idx];
            unsigned b = d >> BSH;
            key[j] = (s << BSH) | (d & BMSK);
            bkt[j] = b;
            atomicAdd(&h[b], 1u);
        }
    }
    __syncthreads();
    // exclusive scan of roundup16(h) over 256 entries: wave shfl scan, 2 barriers
    unsigned pv = 0, px = 0;
    if (tid < MAXNB) {
        pv = roundup16(h[tid]);
        px = pv;
#pragma unroll
        for (int off = 1; off < 64; off <<= 1) {
            unsigned t = __shfl_up(px, off, 64);
            if ((tid & 63) >= off) px += t;
        }
        if ((tid & 63) == 63) wsum[tid >> 6] = px;
    }
    __syncthreads();
    if (tid < 8) {
        unsigned acc = 0;
        for (int k = 0; k < tid; ++k) acc += wsum[k];
        wbase[tid] = acc;
    }
    __syncthreads();
    if (tid < MAXNB) {
        unsigned ex = px - pv + wbase[tid >> 6];
        lbase[tid] = ex;
        if (tid < nb && h[tid])
            bs_[tid] = (unsigned)(tid * CAP) + atomicAdd(&bfill[tid * BPAD], roundup16(h[tid]));
    }
    __syncthreads();
    // scatter from registers into LDS (node-agnostic, bucket-sorted)
#pragma unroll
    for (int j = 0; j < 16; ++j) {
        int idx = j * 512 + tid;
        if (idx < cn) {
            unsigned b = bkt[j];
            unsigned pos = lbase[b] + atomicAdd(&cur[b], 1u);
            sorted[pos] = key[j];
        }
    }
    // sentinel-fill ONLY the pad slots (disjoint from scatter range)
    for (int b = tid; b < nb; b += 512) {
        unsigned hb = h[b];
        if (!hb) continue;
        unsigned k0 = lbase[b] + hb;
        unsigned k1 = lbase[b] + roundup16(hb);
        for (unsigned k = k0; k < k1; ++k) sorted[k] = SENT;
    }
    __syncthreads();
    // burst copy: one wave per bucket, uint4 contiguous stores
    int wid = tid >> 6;
    int lane = tid & 63;
    for (int b = wid; b < nb; b += 8) {
        unsigned np = roundup16(h[b]) >> 2;   // uint4 count
        if (!np) continue;
        const uint4* sp = reinterpret_cast<const uint4*>(&sorted[lbase[b]]);
        uint4* gp = reinterpret_cast<uint4*>(&pairs[bs_[b]]);
        for (unsigned k = lane; k < np; k += 64) gp[k] = sp[k];
    }
}

// per-bucket: node hist (uint4 pass) + wave scan -> cnt/dis/rstart + xd,
// node-sorted scatter (uint4 pass) of src into esrc
__global__ __launch_bounds__(512) void k_binB(const unsigned* __restrict__ pairs,
                                              const unsigned* __restrict__ bfill,
                                              const float* __restrict__ x,
                                              int* __restrict__ cnt, float* __restrict__ dis,
                                              int* __restrict__ rstart, int* __restrict__ esrc,
                                              unsigned* __restrict__ xd, int N) {
    __shared__ unsigned h[NPB];
    __shared__ unsigned sc_[NPB];
    __shared__ unsigned cur[NPB];
    __shared__ unsigned wsum[8];
    __shared__ unsigned wbase[8];
    int tid = threadIdx.x, b = blockIdx.x;
    h[tid] = 0;
    cur[tid] = 0;
    __syncthreads();
    int r0 = b * CAP;
    int n4 = (int)bfill[b * BPAD] >> 2;
    const uint4* p4 = reinterpret_cast<const uint4*>(pairs + r0);
    for (int i = tid; i < n4; i += 512) {
        uint4 p = p4[i];
        if (p.x != SENT) atomicAdd(&h[p.x & BMSK], 1u);
        if (p.y != SENT) atomicAdd(&h[p.y & BMSK], 1u);
        if (p.z != SENT) atomicAdd(&h[p.z & BMSK], 1u);
        if (p.w != SENT) atomicAdd(&h[p.w & BMSK], 1u);
    }
    __syncthreads();
    // exclusive scan over 512 entries: wave shfl scan, 2 barriers
    unsigned v = h[tid];
    unsigned x2 = v;
#pragma unroll
    for (int off = 1; off < 64; off <<= 1) {
        unsigned t = __shfl_up(x2, off, 64);
        if ((tid & 63) >= off) x2 += t;
    }
    if ((tid & 63) == 63) wsum[tid >> 6] = x2;
    __syncthreads();
    if (tid < 8) {
        unsigned acc = 0;
        for (int k = 0; k < tid; ++k) acc += wsum[k];
        wbase[tid] = acc;
    }
    __syncthreads();
    unsigned ex = x2 - v + wbase[tid >> 6];
    sc_[tid] = ex;
    int node = (b << BSH) + tid;
    if (node < N) {
        float d = rsqrtf((float)(v + 1));
        cnt[node] = (int)v;
        dis[node] = d;
        rstart[node] = r0 + (int)ex;
        const float4* xp = reinterpret_cast<const float4*>(x + (size_t)node * F0);
        unsigned pk[8];
#pragma unroll
        for (int q = 0; q < 4; ++q) {
            float4 vv = xp[q];
            pk[2 * q + 0] = f2bf(d * vv.x) | (f2bf(d * vv.y) << 16);
            pk[2 * q + 1] = f2bf(d * vv.z) | (f2bf(d * vv.w) << 16);
        }
        uint4* o = reinterpret_cast<uint4*>(xd + (size_t)node * 8);
        o[0] = make_uint4(pk[0], pk[1], pk[2], pk[3]);
        o[1] = make_uint4(pk[4], pk[5], pk[6], pk[7]);
    }
    __syncthreads();
    for (int i = tid; i < n4; i += 512) {
        uint4 p = p4[i];
        if (p.x != SENT) { unsigned l = p.x & BMSK; unsigned o_ = atomicAdd(&cur[l], 1u); esrc[r0 + sc_[l] + o_] = (int)(p.x >> BSH); }
        if (p.y != SENT) { unsigned l = p.y & BMSK; unsigned o_ = atomicAdd(&cur[l], 1u); esrc[r0 + sc_[l] + o_] = (int)(p.y >> BSH); }
        if (p.z != SENT) { unsigned l = p.z & BMSK; unsigned o_ = atomicAdd(&cur[l], 1u); esrc[r0 + sc_[l] + o_] = (int)(p.z >> BSH); }
        if (p.w != SENT) { unsigned l = p.w & BMSK; unsigned o_ = atomicAdd(&cur[l], 1u); esrc[r0 + sc_[l] + o_] = (int)(p.w >> BSH); }
    }
}

// fused layer1: 8 lanes/node gather-aggregate xd (1 u32/lane = 32B/row),
// then y exchange via wave-local LDS and in-register MLP -> g2
__global__ void k_layer1(const unsigned* __restrict__ xd, const int* __restrict__ cnt,
                         const int* __restrict__ rstart, const int* __restrict__ esrc,
                         const float* __restrict__ dis, const float* __restrict__ b1,
                         const float* __restrict__ W1, const float* __restrict__ W2,
                         float* __restrict__ g2, int N) {
    __shared__ float w1[F0 * F1];
    __shared__ float w2[F1 * F2];
    __shared__ float bb[F1];
    __shared__ float ymat[32][17];   // 32 nodes/block, +1 pad
    for (int j = threadIdx.x; j < F0 * F1; j += blockDim.x) w1[j] = W1[j];
    for (int j = threadIdx.x; j < F1 * F2; j += blockDim.x) w2[j] = W2[j];
    for (int j = threadIdx.x; j < F1; j += blockDim.x) bb[j] = b1[j];
    __syncthreads();
    int t = blockIdx.x * blockDim.x + threadIdx.x;
    int v = t >> 3;
    int q = t & 7;
    if (v >= N) return;
    const unsigned* base = xd + q;             // row stride 8 u32
    unsigned sw = base[(size_t)v * 8];         // self loop xd[v]
    float a0 = bf2f(sw & 0xffffu);
    float a1 = bf2f(sw >> 16);
    int beg = rstart[v];
    int n = cnt[v];
    int n8 = n & ~7;
    for (int j = 0; j < n8; j += 8) {
        int idx = esrc[beg + j + q];           // 8 distinct edges across group
#pragma unroll
        for (int u = 0; u < 8; ++u) {
            int s = __shfl(idx, u, 8);
            unsigned a = base[(size_t)s * 8];
            a0 += bf2f(a & 0xffffu);
            a1 += bf2f(a >> 16);
        }
    }
    for (int j = n8; j < n; ++j) {             // tail: uniform load
        int s = esrc[beg + j];
        unsigned a = base[(size_t)s * 8];
        a0 += bf2f(a & 0xffffu);
        a1 += bf2f(a >> 16);
    }
    // exchange y within the 8-lane group (wave-local LDS, lockstep)
    int ln = threadIdx.x >> 3;
    ymat[ln][2 * q + 0] = a0;
    ymat[ln][2 * q + 1] = a1;
    float y[F0];
#pragma unroll
    for (int k = 0; k < F0; ++k) y[k] = ymat[ln][k];
    float d = dis[v];
    float p0 = 0.0f, p1 = 0.0f;
#pragma unroll
    for (int u = 0; u < 4; ++u) {
        int jf = q * 4 + u;                    // 32 features across 8 lanes x 4
        float s = 0.0f;
#pragma unroll
        for (int k = 0; k < F0; ++k) s = fmaf(y[k], w1[k * F1 + jf], s);
        float r = fmaxf(fmaf(d, s, bb[jf]), 0.0f);
        p0 = fmaf(r, w2[jf * F2 + 0], p0);
        p1 = fmaf(r, w2[jf * F2 + 1], p1);
    }
#pragma unroll
    for (int off = 1; off < 8; off <<= 1) {
        p0 += __shfl_xor(p0, off);
        p1 += __shfl_xor(p1, off);
    }
    if (q == 0) {
        g2[(size_t)v * F2 + 0] = d * p0;
        g2[(size_t)v * F2 + 1] = d * p1;
    }
}

// fused layer2 aggregate + output: 4 lanes per node, strided edges, 4x unroll
__global__ void k_out2(const float* __restrict__ g2, const int* __restrict__ cnt,
                       const int* __restrict__ rstart, const int* __restrict__ esrc,
                       const float* __restrict__ dis, const float* __restrict__ b2,
                       float* __restrict__ out, int N) {
    int t = blockIdx.x * blockDim.x + threadIdx.x;
    int v = t >> 2;
    int l = t & 3;
    if (v >= N) return;
    float o0 = 0.0f, o1 = 0.0f;
    int beg = rstart[v];
    int end = beg + cnt[v];
    int j = beg + l;
    for (; j + 12 < end; j += 16) {        // 4 independent gathers in flight
        int s0 = esrc[j];
        int s1 = esrc[j + 4];
        int s2 = esrc[j + 8];
        int s3 = esrc[j + 12];
        float2 a0 = *reinterpret_cast<const float2*>(g2 + (size_t)s0 * F2);
        float2 a1 = *reinterpret_cast<const float2*>(g2 + (size_t)s1 * F2);
        float2 a2 = *reinterpret_cast<const float2*>(g2 + (size_t)s2 * F2);
        float2 a3 = *reinterpret_cast<const float2*>(g2 + (size_t)s3 * F2);
        o0 += a0.x + a1.x + a2.x + a3.x;
        o1 += a0.y + a1.y + a2.y + a3.y;
    }
    for (; j < end; j += 4) {
        int s = esrc[j];
        const float2 a = *reinterpret_cast<const float2*>(g2 + (size_t)s * F2);
        o0 += a.x; o1 += a.y;
    }
#pragma unroll
    for (int off = 1; off < 4; off <<= 1) {
        o0 += __shfl_xor(o0, off);
        o1 += __shfl_xor(o1, off);
    }
    if (l == 0) {
        float d = dis[v];
        const float2 self = *reinterpret_cast<const float2*>(g2 + (size_t)v * F2);
        out[(size_t)v * F2 + 0] = fmaf(d, o0 + self.x, b2[0]);
        out[(size_t)v * F2 + 1] = fmaf(d, o1 + self.y, b2[1]);
    }
}

extern "C" void kernel_launch(void* const* d_in, const int* in_sizes, int n_in,
                              void* d_out, int out_size, void* d_ws, size_t ws_size,
                              hipStream_t stream) {
    const float* x  = (const float*)d_in[0];
    const int* ei   = (const int*)d_in[1];
    const float* W1 = (const float*)d_in[2];
    const float* b1 = (const float*)d_in[3];
    const float* W2 = (const float*)d_in[4];
    const float* b2 = (const float*)d_in[5];
    float* out = (float*)d_out;

    const int N = in_sizes[0] / F0;          // 100000
    const int E = in_sizes[1] / 2;           // 3200000
    const int* src = ei;
    const int* dst = ei + E;
    const int nb = (N + BMSK) >> BSH;        // 196 buckets of 512 nodes
    const int nchunk = (E + EPB - 1) / EPB;  // 391 chunks

    // workspace layout (u32 units); pairs 16B-aligned
    unsigned* bfill = (unsigned*)d_ws;                    // MAXNB*BPAD (16KB)
    unsigned* pairs = bfill + MAXNB * BPAD;               // nb*CAP (~19.3MB)
    int* esrc       = (int*)(pairs + (size_t)nb * CAP);   // nb*CAP (~19.3MB)
    unsigned* xd    = (unsigned*)(esrc + (size_t)nb * CAP); // 8N (32B rows)
    float* dis      = (float*)(xd + (size_t)8 * N);       // N
    int* cnt        = (int*)(dis + N);                    // N
    int* rstart     = cnt + N;                            // N
    float* g2       = (float*)(rstart + N);               // 2N
    // total ~ 44 MB

    const int B = 256;
    k_zero<<<MAXNB * BPAD / 256, 256, 0, stream>>>(bfill);
    k_binA<<<nchunk, 512, 0, stream>>>(src, dst, bfill, pairs, E, nb);
    k_binB<<<nb, 512, 0, stream>>>(pairs, bfill, x, cnt, dis, rstart, esrc, xd, N);
    k_layer1<<<(N * 8 + B - 1) / B, B, 0, stream>>>(xd, cnt, rstart, esrc, dis, b1, W1, W2, g2, N);
    k_out2<<<(N * 4 + B - 1) / B, B, 0, stream>>>(g2, cnt, rstart, esrc, dis, b2, out, N);
}